// Round 1
// baseline (120.434 us; speedup 1.0000x reference)
//
#include <hip/hip_runtime.h>

// Problem constants
#define TABLES 4608      // OC*IC*KH*KW = 32*16*9
#define OC_ 32
#define IC_ 16
#define H_ 32
#define W_ 32
#define B_ 8
#define OH_ 32
#define OW_ 32
#define TPO 144          // tables per output channel = IC*KH*KW

// LDS tile geometry for the compute kernel: 8 output rows + 2 halo rows,
// 32 cols + 2 halo cols -> 10 x 34 per channel, zero-padded borders.
#define ROWS_PER_WG 8
#define TR 10
#define TC 34
#define CH_STRIDE (TR * TC)          // 340 floats per channel plane
#define TILE_F (IC_ * CH_STRIDE)     // 5440 floats = 21760 B LDS
#define OCG 2                        // output channels per workgroup

struct __align__(16) Rec {
    int   off0;   // LDS offset for x0 (relative to position base)
    int   off1;   // LDS offset for x1
    float bb;     // coeff of x0
    float cc;     // coeff of x1
    float dd;     // coeff of x0*x1
    int   pad0, pad1, pad2;          // pad to 32 B for clean s_load_dwordx8
};

// Kernel 1: build per-table bilinear records + per-oc bias (sum of constant terms).
__global__ void setup_kernel(const float* __restrict__ w_luts,
                             const int*   __restrict__ mask_c,
                             const int*   __restrict__ mask_kh,
                             const int*   __restrict__ mask_kw,
                             Rec*         __restrict__ recs,
                             float*       __restrict__ bias) {
    int t = blockIdx.x * blockDim.x + threadIdx.x;
    if (t >= TABLES) return;
    float w0 = w_luts[4 * t + 0];
    float w1 = w_luts[4 * t + 1];
    float w2 = w_luts[4 * t + 2];
    float w3 = w_luts[4 * t + 3];
    // basis_e = prod_k (1 + x_k * tt[k][e]) / 2, tt[k][e] = 2*((e>>k)&1)-1
    // => out_t = a + b*x0 + c*x1 + d*x0*x1
    float a = 0.25f * ( w0 + w1 + w2 + w3);
    float b = 0.25f * (-w0 + w1 - w2 + w3);
    float c = 0.25f * (-w0 - w1 + w2 + w3);
    float d = 0.25f * ( w0 - w1 - w2 + w3);
    int m0 = 2 * t, m1 = 2 * t + 1;
    Rec r;
    // gather addr inside tile = base(lo*TC+ow) + c*CH_STRIDE + kh*TC + kw
    r.off0 = mask_c[m0] * CH_STRIDE + mask_kh[m0] * TC + mask_kw[m0];
    r.off1 = mask_c[m1] * CH_STRIDE + mask_kh[m1] * TC + mask_kw[m1];
    r.bb = b; r.cc = c; r.dd = d;
    r.pad0 = 0; r.pad1 = 0; r.pad2 = 0;
    recs[t] = r;
    atomicAdd(&bias[t / TPO], a);   // bias[oc] = sum of 'a' over its 144 tables
}

// Kernel 2: block = (oh-tile, oc-group, batch); thread = one (oh,ow) position.
__global__ __launch_bounds__(256)
void conv_kernel(const float* __restrict__ input,
                 const Rec*   __restrict__ recs,
                 const float* __restrict__ bias,
                 float*       __restrict__ out) {
    __shared__ float tile[TILE_F];
    const int oh0 = blockIdx.x * ROWS_PER_WG;
    const int ocg = blockIdx.y;
    const int b   = blockIdx.z;
    const int tid = threadIdx.x;

    // 1) zero the tile (covers padding cols 0/33 and out-of-range halo rows)
    for (int i = tid; i < TILE_F; i += 256) tile[i] = 0.0f;
    __syncthreads();

    // 2) fill interior: 16 ch x 10 rows x 32 cols, float4 global loads
    const float* inb = input + b * (IC_ * H_ * W_);
    for (int u = tid; u < IC_ * TR * 8; u += 256) {   // 1280 float4 units
        int ch  = u / 80;
        int rem = u - ch * 80;
        int r   = rem >> 3;
        int c4  = (rem & 7) * 4;
        int grow = oh0 + r - 1;
        if ((unsigned)grow < (unsigned)H_) {
            const float4 v = *reinterpret_cast<const float4*>(inb + (ch * H_ + grow) * W_ + c4);
            float* dst = &tile[ch * CH_STRIDE + r * TC + 1 + c4];
            dst[0] = v.x; dst[1] = v.y; dst[2] = v.z; dst[3] = v.w;
        }
    }
    __syncthreads();

    // 3) hot loop: 2 ocs x 144 tables, records via uniform (scalar) loads
    const int lo   = tid >> 5;          // 0..7 local row
    const int ow   = tid & 31;          // 0..31 col
    const int base = lo * TC + ow;
    const int oh   = oh0 + lo;

    for (int j = 0; j < OCG; ++j) {
        const int oc = ocg * OCG + j;
        const Rec* __restrict__ rp = recs + oc * TPO;
        float acc = 0.0f;
        #pragma unroll 8
        for (int t = 0; t < TPO; ++t) {
            Rec r = rp[t];                      // uniform -> s_load, SMEM pipe
            float x0 = tile[base + r.off0];
            float x1 = tile[base + r.off1];
            acc = fmaf(r.bb, x0, acc);
            float u2 = fmaf(r.dd, x0, r.cc);
            acc = fmaf(x1, u2, acc);
        }
        out[((b * OC_ + oc) * OH_ + oh) * OW_ + ow] = acc + bias[oc];
    }
}

extern "C" void kernel_launch(void* const* d_in, const int* in_sizes, int n_in,
                              void* d_out, int out_size, void* d_ws, size_t ws_size,
                              hipStream_t stream) {
    const float* input  = (const float*)d_in[0];
    const float* w_luts = (const float*)d_in[1];
    const int*   mask_c = (const int*)d_in[2];
    const int*   mask_kh= (const int*)d_in[3];
    const int*   mask_kw= (const int*)d_in[4];
    float* out = (float*)d_out;

    Rec*   recs = (Rec*)d_ws;
    float* bias = (float*)((char*)d_ws + TABLES * sizeof(Rec));

    // ws is re-poisoned to 0xAA before every timed call: zero the bias slots.
    hipMemsetAsync(bias, 0, OC_ * sizeof(float), stream);

    setup_kernel<<<dim3((TABLES + 255) / 256), dim3(256), 0, stream>>>(
        w_luts, mask_c, mask_kh, mask_kw, recs, bias);

    conv_kernel<<<dim3(OH_ / ROWS_PER_WG, OC_ / OCG, B_), dim3(256), 0, stream>>>(
        input, recs, bias, out);
}

// Round 2
// 77.967 us; speedup vs baseline: 1.5447x; 1.5447x over previous
//
#include <hip/hip_runtime.h>

// Problem constants
#define TABLES 4608      // OC*IC*KH*KW = 32*16*9
#define OC_ 32
#define IC_ 16
#define H_ 32
#define W_ 32
#define B_ 8
#define OH_ 32
#define OW_ 32
#define TPO 144          // tables per output channel = IC*KH*KW

// LDS tile: 8 output rows + 2 halo rows, 32 cols + 2 halo cols, zero-padded.
#define ROWS_PER_WG 8
#define TR 10
#define TC 34
#define CH_STRIDE (TR * TC)          // 340 floats per channel plane
#define TILE_F (IC_ * CH_STRIDE)     // 5440 floats = 21760 B

// Per-table bilinear record, 32 B so it reads as 2x ds_read_b128.
// out_t = aa + bb*x0 + cc*x1 + dd*x0*x1
struct __align__(16) Rec {
    int   off0;   // LDS gather offset for x0 (relative to position base)
    int   off1;   // LDS gather offset for x1
    float bb;
    float cc;
    float dd;
    float aa;
    int   pad0, pad1;
};

// Single fused kernel. Block = (8-row tile, oc, batch); thread = one (oh,ow).
// Recs are recomputed per block (cheap) and staged in LDS so the hot loop is
// DS-only on lgkmcnt (in-order -> fine-grained waitcnt, software-pipelinable).
// Mixing s_load (SMEM) with ds_read forces lgkmcnt(0) drains on gfx9 — avoided.
__global__ __launch_bounds__(256)
void conv_kernel(const float* __restrict__ input,
                 const float* __restrict__ w_luts,
                 const int*   __restrict__ mask_c,
                 const int*   __restrict__ mask_kh,
                 const int*   __restrict__ mask_kw,
                 float*       __restrict__ out) {
    __shared__ float tile[TILE_F];
    __shared__ Rec   srec[TPO];

    const int oh0 = blockIdx.x * ROWS_PER_WG;
    const int oc  = blockIdx.y;
    const int b   = blockIdx.z;
    const int tid = threadIdx.x;

    // --- stage input tile: 16 ch x 10 rows x 32 interior cols, float4 loads;
    //     out-of-range halo rows get zeros in the same pass.
    const float* inb = input + b * (IC_ * H_ * W_);
    for (int u = tid; u < IC_ * TR * 8; u += 256) {   // 1280 float4 units, 5 iters
        int ch  = u / 80;
        int rem = u - ch * 80;
        int r   = rem >> 3;
        int c4  = (rem & 7) * 4;
        int grow = oh0 + r - 1;
        float4 v = make_float4(0.f, 0.f, 0.f, 0.f);
        if ((unsigned)grow < (unsigned)H_)
            v = *reinterpret_cast<const float4*>(inb + (ch * H_ + grow) * W_ + c4);
        float* dst = &tile[ch * CH_STRIDE + r * TC + 1 + c4];
        dst[0] = v.x; dst[1] = v.y; dst[2] = v.z; dst[3] = v.w;
    }
    // zero the halo columns 0 and 33 (16 ch x 10 rows x 2 cols = 320)
    for (int i = tid; i < IC_ * TR * 2; i += 256) {
        int ch  = i / 20;
        int rem = i - ch * 20;
        int r   = rem >> 1;
        int cc  = (rem & 1) ? (TC - 1) : 0;
        tile[ch * CH_STRIDE + r * TC + cc] = 0.f;
    }
    // --- build this oc's 144 records in-block (threads 0..143)
    if (tid < TPO) {
        int t  = oc * TPO + tid;
        const float4 w = *reinterpret_cast<const float4*>(w_luts + 4 * t);
        int m0 = 2 * t, m1 = m0 + 1;
        Rec r;
        r.off0 = mask_c[m0] * CH_STRIDE + mask_kh[m0] * TC + mask_kw[m0];
        r.off1 = mask_c[m1] * CH_STRIDE + mask_kh[m1] * TC + mask_kw[m1];
        // basis_e = prod_k (1 + x_k*tt[k][e])/2  =>  a + b*x0 + c*x1 + d*x0*x1
        r.aa = 0.25f * ( w.x + w.y + w.z + w.w);
        r.bb = 0.25f * (-w.x + w.y - w.z + w.w);
        r.cc = 0.25f * (-w.x - w.y + w.z + w.w);
        r.dd = 0.25f * ( w.x - w.y - w.z + w.w);
        r.pad0 = 0; r.pad1 = 0;
        srec[tid] = r;
    }
    __syncthreads();

    // --- hot loop: 144 tables, all LDS (rec broadcast b128 + 2 gather b32)
    const int lo   = tid >> 5;          // local row 0..7
    const int ow   = tid & 31;          // col 0..31
    const int base = lo * TC + ow;
    const int oh   = oh0 + lo;

    float acc = 0.0f;
    #pragma unroll 8
    for (int t = 0; t < TPO; ++t) {
        Rec r = srec[t];                 // broadcast, conflict-free
        float x0 = tile[base + r.off0];  // consecutive lanes -> 2-way alias, free
        float x1 = tile[base + r.off1];
        acc += r.aa;
        acc = fmaf(r.bb, x0, acc);
        acc = fmaf(x1, fmaf(r.dd, x0, r.cc), acc);
    }
    out[((b * OC_ + oc) * OH_ + oh) * OW_ + ow] = acc;
}

extern "C" void kernel_launch(void* const* d_in, const int* in_sizes, int n_in,
                              void* d_out, int out_size, void* d_ws, size_t ws_size,
                              hipStream_t stream) {
    const float* input   = (const float*)d_in[0];
    const float* w_luts  = (const float*)d_in[1];
    const int*   mask_c  = (const int*)d_in[2];
    const int*   mask_kh = (const int*)d_in[3];
    const int*   mask_kw = (const int*)d_in[4];
    float* out = (float*)d_out;

    conv_kernel<<<dim3(OH_ / ROWS_PER_WG, OC_, B_), dim3(256), 0, stream>>>(
        input, w_luts, mask_c, mask_kh, mask_kw, out);
}

// Round 3
// 72.731 us; speedup vs baseline: 1.6559x; 1.0720x over previous
//
#include <hip/hip_runtime.h>

// Problem constants
#define OC_ 32
#define IC_ 16
#define H_ 32
#define W_ 32
#define B_ 8
#define TPO 144          // tables per output channel = IC*KH*KW

// LDS tile: 16 output rows + 2 halo rows, 32 cols + 2 halo cols, zero-padded.
#define ROWS_PER_WG 16
#define TR 18
#define TC 34
#define CH_STRIDE (TR * TC)          // 612 floats per channel plane
#define TILE_F (IC_ * CH_STRIDE)     // 9792 floats = 39168 B

// 16-B packed record -> ONE ds_read_b128 per table (was 2x b128 for 32 B).
// offs = (off0*4) | (off1*4 << 16)   [byte offsets; max 37000 < 65536]
// out_t = bias_term(aa, folded per-block) + bb*x0 + cc*x1 + dd*x0*x1
struct alignas(16) Rec4 { int offs; float bb, cc, dd; };

__global__ __launch_bounds__(256)
void conv_kernel(const float* __restrict__ input,
                 const float* __restrict__ w_luts,
                 const int*   __restrict__ mask_c,
                 const int*   __restrict__ mask_kh,
                 const int*   __restrict__ mask_kw,
                 float*       __restrict__ out) {
    __shared__ float tile[TILE_F];
    __shared__ Rec4  srec[TPO];
    __shared__ float sAA[TPO];
    __shared__ float sP[8];

    const int oh0 = blockIdx.x * ROWS_PER_WG;
    const int oc  = blockIdx.y;
    const int b   = blockIdx.z;
    const int tid = threadIdx.x;

    // --- build this oc's 144 packed records (threads 0..143)
    if (tid < TPO) {
        int t = oc * TPO + tid;
        const float4 w = *reinterpret_cast<const float4*>(w_luts + 4 * t);
        int m0 = 2 * t, m1 = m0 + 1;
        int off0 = mask_c[m0] * CH_STRIDE + mask_kh[m0] * TC + mask_kw[m0];
        int off1 = mask_c[m1] * CH_STRIDE + mask_kh[m1] * TC + mask_kw[m1];
        Rec4 r;
        r.offs = (off0 * 4) | ((off1 * 4) << 16);
        r.bb = 0.25f * (-w.x + w.y - w.z + w.w);
        r.cc = 0.25f * (-w.x - w.y + w.z + w.w);
        r.dd = 0.25f * ( w.x - w.y - w.z + w.w);
        srec[tid] = r;
        sAA[tid]  = 0.25f * (w.x + w.y + w.z + w.w);   // constant term -> bias
    }

    // --- stage input tile: 16 ch x 18 rows x 32 interior cols, float4 loads
    const float* inb = input + b * (IC_ * H_ * W_);
    for (int u = tid; u < IC_ * TR * 8; u += 256) {   // 2304 float4 units, 9 iters
        int ch  = u / (TR * 8);
        int rem = u - ch * (TR * 8);
        int r   = rem >> 3;
        int c4  = (rem & 7) * 4;
        int grow = oh0 + r - 1;
        float4 v = make_float4(0.f, 0.f, 0.f, 0.f);
        if ((unsigned)grow < (unsigned)H_)
            v = *reinterpret_cast<const float4*>(inb + (ch * H_ + grow) * W_ + c4);
        float* dst = &tile[ch * CH_STRIDE + r * TC + 1 + c4];
        dst[0] = v.x; dst[1] = v.y; dst[2] = v.z; dst[3] = v.w;
    }
    // zero halo columns 0 and 33
    for (int i = tid; i < IC_ * TR * 2; i += 256) {
        int ch  = i / (TR * 2);
        int rem = i - ch * (TR * 2);
        int r   = rem >> 1;
        int cc2 = (rem & 1) ? (TC - 1) : 0;
        tile[ch * CH_STRIDE + r * TC + cc2] = 0.f;
    }
    __syncthreads();

    // --- fold constant terms into one per-block bias (cheap tree reduce)
    if (tid < 8) {
        float s = 0.f;
        #pragma unroll
        for (int i = 0; i < 18; ++i) s += sAA[tid * 18 + i];
        sP[tid] = s;
    }
    __syncthreads();
    const float bias = ((sP[0] + sP[1]) + (sP[2] + sP[3]))
                     + ((sP[4] + sP[5]) + (sP[6] + sP[7]));

    // --- hot loop: 144 tables x 2 spatial positions per thread, DS-only
    const int rl    = tid >> 5;                 // 0..7
    const int ow    = tid & 31;                 // 0..31
    const int baseA = (rl * TC + ow) * 4;       // byte offset, rows rl
    const int baseB = baseA + 8 * TC * 4;       // rows rl+8
    const char* tbase = (const char*)tile;

    float accA = 0.f, accB = 0.f;
    #pragma unroll 8
    for (int t = 0; t < TPO; ++t) {
        const int4 q = *reinterpret_cast<const int4*>(&srec[t]);  // 1x ds_read_b128, broadcast
        const int   offs = q.x;
        const float bb = __int_as_float(q.y);
        const float cc = __int_as_float(q.z);
        const float dd = __int_as_float(q.w);
        const int o0 = offs & 0xffff;
        const int o1 = ((unsigned)offs) >> 16;
        float x0a = *reinterpret_cast<const float*>(tbase + baseA + o0);
        float x1a = *reinterpret_cast<const float*>(tbase + baseA + o1);
        float x0b = *reinterpret_cast<const float*>(tbase + baseB + o0);
        float x1b = *reinterpret_cast<const float*>(tbase + baseB + o1);
        accA = fmaf(bb, x0a, accA);
        accA = fmaf(x1a, fmaf(dd, x0a, cc), accA);
        accB = fmaf(bb, x0b, accB);
        accB = fmaf(x1b, fmaf(dd, x0b, cc), accB);
    }
    const int ohA = oh0 + rl;
    out[((b * OC_ + oc) * H_ + ohA    ) * W_ + ow] = accA + bias;
    out[((b * OC_ + oc) * H_ + ohA + 8) * W_ + ow] = accB + bias;
}

extern "C" void kernel_launch(void* const* d_in, const int* in_sizes, int n_in,
                              void* d_out, int out_size, void* d_ws, size_t ws_size,
                              hipStream_t stream) {
    const float* input   = (const float*)d_in[0];
    const float* w_luts  = (const float*)d_in[1];
    const int*   mask_c  = (const int*)d_in[2];
    const int*   mask_kh = (const int*)d_in[3];
    const int*   mask_kw = (const int*)d_in[4];
    float* out = (float*)d_out;

    conv_kernel<<<dim3(H_ / ROWS_PER_WG, OC_, B_), dim3(256), 0, stream>>>(
        input, w_luts, mask_c, mask_kh, mask_kw, out);
}

// Round 4
// 71.350 us; speedup vs baseline: 1.6879x; 1.0194x over previous
//
#include <hip/hip_runtime.h>

// Problem constants
#define OC_ 32
#define IC_ 16
#define H_ 32
#define W_ 32
#define B_ 8
#define TPO 144          // tables per output channel = IC*KH*KW

// LDS tile: 16 output rows + 2 halo rows; TC=40 so that the row-pair stride
// (8 rows * 40 dwords = 320 = 5*64) lets the compiler merge the two gathers
// tile[a] / tile[a+320] into ONE ds_read2st64_b32 (offset0:0 offset1:5).
// Cols: 0 = left halo, 1..32 = interior, 33 = right halo, 34..39 = dead pad.
#define ROWS_PER_WG 16
#define TR 18
#define TC 40
#define CH_STRIDE (TR * TC)          // 720 dwords per channel plane
#define TILE_F (IC_ * CH_STRIDE)     // 11520 floats = 46080 B
#define ROWPAIR (8 * TC)             // 320 dwords between paired rows

#define PF 8                         // rec prefetch depth (batch)
#define SREC_N 152                   // 144 used + 8 pad so prefetch never reads OOB

// 16-B packed record -> one ds_read_b128 (broadcast) per table.
// offs = off0 | (off1 << 16), dword offsets (max 10882 < 32768).
// out_t = aa(folded to per-block bias) + bb*x0 + cc*x1 + dd*x0*x1
struct alignas(16) Rec4 { int offs; float bb, cc, dd; };

__global__ __launch_bounds__(256)
void conv_kernel(const float* __restrict__ input,
                 const float* __restrict__ w_luts,
                 const int*   __restrict__ mask_c,
                 const int*   __restrict__ mask_kh,
                 const int*   __restrict__ mask_kw,
                 float*       __restrict__ out) {
    __shared__ float tile[TILE_F];
    __shared__ Rec4  srec[SREC_N];
    __shared__ float sAA[TPO];
    __shared__ float sP[8];

    const int oh0 = blockIdx.x * ROWS_PER_WG;   // grid.x = 2
    const int oc  = blockIdx.y;
    const int b   = blockIdx.z;
    const int tid = threadIdx.x;

    // --- build this oc's 144 packed records (threads 0..143)
    if (tid < TPO) {
        int t = oc * TPO + tid;
        const float4 w = *reinterpret_cast<const float4*>(w_luts + 4 * t);
        int m0 = 2 * t, m1 = m0 + 1;
        int off0 = mask_c[m0] * CH_STRIDE + mask_kh[m0] * TC + mask_kw[m0];
        int off1 = mask_c[m1] * CH_STRIDE + mask_kh[m1] * TC + mask_kw[m1];
        Rec4 r;
        r.offs = off0 | (off1 << 16);
        r.bb = 0.25f * (-w.x + w.y - w.z + w.w);
        r.cc = 0.25f * (-w.x - w.y + w.z + w.w);
        r.dd = 0.25f * ( w.x - w.y - w.z + w.w);
        srec[tid] = r;
        sAA[tid]  = 0.25f * (w.x + w.y + w.z + w.w);
    }

    // --- stage input tile: 16 ch x 18 rows x 32 interior cols, float4 loads
    const float* inb = input + b * (IC_ * H_ * W_);
    for (int u = tid; u < IC_ * TR * 8; u += 256) {   // 2304 float4 units
        int ch  = u / (TR * 8);
        int rem = u - ch * (TR * 8);
        int r   = rem >> 3;
        int c4  = (rem & 7) * 4;
        int grow = oh0 + r - 1;
        float4 v = make_float4(0.f, 0.f, 0.f, 0.f);
        if ((unsigned)grow < (unsigned)H_)
            v = *reinterpret_cast<const float4*>(inb + (ch * H_ + grow) * W_ + c4);
        float* dst = &tile[ch * CH_STRIDE + r * TC + 1 + c4];
        dst[0] = v.x; dst[1] = v.y; dst[2] = v.z; dst[3] = v.w;
    }
    // zero halo columns 0 and 33 (cols 34..39 are never read)
    for (int i = tid; i < IC_ * TR * 2; i += 256) {
        int ch  = i / (TR * 2);
        int rem = i - ch * (TR * 2);
        int r   = rem >> 1;
        int cc2 = (rem & 1) ? 33 : 0;
        tile[ch * CH_STRIDE + r * TC + cc2] = 0.f;
    }
    __syncthreads();

    // --- fold constant terms into one per-block bias
    if (tid < 8) {
        float s = 0.f;
        #pragma unroll
        for (int i = 0; i < 18; ++i) s += sAA[tid * 18 + i];
        sP[tid] = s;
    }
    __syncthreads();
    const float bias = ((sP[0] + sP[1]) + (sP[2] + sP[3]))
                     + ((sP[4] + sP[5]) + (sP[6] + sP[7]));

    // --- hot loop: 144 tables x 2 row-paired positions per thread.
    // Recs prefetched one batch (PF=8) ahead in registers so the rec->address->
    // gather serial chain overlaps the previous batch's gathers+FMAs
    // (8 waves/CU is too few to hide it by TLP alone — R3's lesson).
    const int rl    = tid >> 5;                 // 0..7 (rows rl and rl+8)
    const int ow    = tid & 31;
    const int baseA = rl * TC + ow;             // dword index
    const int4* sq  = reinterpret_cast<const int4*>(srec);

    float accA = 0.f, accB = 0.f;
    int4 q[PF];
    #pragma unroll
    for (int i = 0; i < PF; ++i) q[i] = sq[i];

    for (int tb = 0; tb < TPO; tb += PF) {
        int4 qn[PF];
        #pragma unroll
        for (int i = 0; i < PF; ++i) qn[i] = sq[tb + PF + i];  // pad makes this in-bounds
        #pragma unroll
        for (int i = 0; i < PF; ++i) {
            const unsigned offs = (unsigned)q[i].x;
            const int o0 = offs & 0xffff;
            const int o1 = offs >> 16;
            // each pair tile[a] / tile[a+320] -> one ds_read2st64_b32
            const float x0a = tile[baseA + o0];
            const float x0b = tile[baseA + o0 + ROWPAIR];
            const float x1a = tile[baseA + o1];
            const float x1b = tile[baseA + o1 + ROWPAIR];
            const float bb = __int_as_float(q[i].y);
            const float cc = __int_as_float(q[i].z);
            const float dd = __int_as_float(q[i].w);
            accA = fmaf(bb, x0a, accA);
            accA = fmaf(x1a, fmaf(dd, x0a, cc), accA);
            accB = fmaf(bb, x0b, accB);
            accB = fmaf(x1b, fmaf(dd, x0b, cc), accB);
        }
        #pragma unroll
        for (int i = 0; i < PF; ++i) q[i] = qn[i];
    }

    const int ohA = oh0 + rl;
    out[((b * OC_ + oc) * H_ + ohA    ) * W_ + ow] = accA + bias;
    out[((b * OC_ + oc) * H_ + ohA + 8) * W_ + ow] = accB + bias;
}

extern "C" void kernel_launch(void* const* d_in, const int* in_sizes, int n_in,
                              void* d_out, int out_size, void* d_ws, size_t ws_size,
                              hipStream_t stream) {
    const float* input   = (const float*)d_in[0];
    const float* w_luts  = (const float*)d_in[1];
    const int*   mask_c  = (const int*)d_in[2];
    const int*   mask_kh = (const int*)d_in[3];
    const int*   mask_kw = (const int*)d_in[4];
    float* out = (float*)d_out;

    conv_kernel<<<dim3(H_ / ROWS_PER_WG, OC_, B_), dim3(256), 0, stream>>>(
        input, w_luts, mask_c, mask_kh, mask_kw, out);
}